// Round 15
// baseline (274.224 us; speedup 1.0000x reference)
//
#include <hip/hip_runtime.h>
#include <math.h>

#define NSLOTS 50
#define T 101
#define SEQ 2048
#define CHUNK 16

// v + dpp_permuted(v), pure VALU
template<int CTRL>
__device__ __forceinline__ float dpp_xadd(float v) {
    int x = __builtin_amdgcn_update_dpp(0, __float_as_int(v), CTRL, 0xF, 0xF, true);
    return v + __int_as_float(x);
}

// Full 64-lane sum -> wave-uniform scalar (validated r8-r14, absmax 0.0)
__device__ __forceinline__ float wsum64(float v) {
    v = dpp_xadd<0xB1>(v);    // xor 1
    v = dpp_xadd<0x4E>(v);    // xor 2
    v = dpp_xadd<0x141>(v);   // xor 4 (row_half_mirror)
    v = dpp_xadd<0x140>(v);   // xor 8 (row_mirror)
    v = dpp_xadd<0x142>(v);   // row_bcast15
    v = dpp_xadd<0x143>(v);   // row_bcast31
    int s = __builtin_amdgcn_readlane(__float_as_int(v), 63);
    return __int_as_float(s);
}

__device__ __forceinline__ float rdl63(float v) {
    return __int_as_float(__builtin_amdgcn_readlane(__float_as_int(v), 63));
}

__device__ __forceinline__ void gl_lds(const float* g, float* lds) {
#if __has_builtin(__builtin_amdgcn_global_load_lds)
    __builtin_amdgcn_global_load_lds((const __attribute__((address_space(1))) void*)g,
        (__attribute__((address_space(3))) void*)lds, 4, 0, 0);
#else
    lds[threadIdx.x & 63] = *g;
#endif
}

__global__ __launch_bounds__(192, 1) void crf_nll_kernel(
    const float* __restrict__ feats,      // [B,S,T]
    const float* __restrict__ cdt,        // [3,5] log-probs
    const float* __restrict__ start_t,    // [T]
    const float* __restrict__ stop_t,     // [T]
    const int*   __restrict__ mask,       // [B,S]
    const int*   __restrict__ tags,       // [B,S]
    float*       __restrict__ out)        // [B]
{
    const int b = blockIdx.x, tid = threadIdx.x;
    const int wave = tid >> 6, l = tid & 63;
    const float* fb = feats + (size_t)b * SEQ * T;
    const int*   mb = mask + (size_t)b * SEQ;
    const int*   tb = tags + (size_t)b * SEQ;

    __shared__ float S[64 * 128];     // ring: step t -> slot (t-1)&63
    __shared__ float2 Gbuf[2][17];    // per-chunk G pairs (double-buffered; [16]=dummy)
    __shared__ float res[2];

    // ---- length (all waves; mask is a prefix of ones) ----
    float mc = 0.f;
    for (int t = l; t < SEQ; t += 64) mc += (float)mb[t];
    const int len    = (int)(wsum64(mc) + 0.5f);
    const int nsteps = len - 1;
    const int nper   = (nsteps + CHUNK - 1) / CHUNK;
    const int nfull  = nsteps / CHUNK;

    const float actm = (l < NSLOTS) ? 1.f : 0.f;
    const int aB = (2*l+1 <= 100) ? 2*l+1 : 100;
    const int aI = (2*l+2 <= 100) ? 2*l+2 : 100;
    const int s1 = (2*l+1 <= 100) ? 2*l+1 : 0;
    const int s2 = (2*l+2 <= 100) ? 2*l+2 : 0;

    const float pOO=__expf(cdt[0]),  pOB=__expf(cdt[1]),  pOI=__expf(cdt[2]);
    const float pBO=__expf(cdt[5]),  pBBs=__expf(cdt[6]), pBIs=__expf(cdt[7]),
                pBBd=__expf(cdt[8]), pBId=__expf(cdt[9]);
    const float pIO=__expf(cdt[10]), pIBs=__expf(cdt[11]), pIIs=__expf(cdt[12]),
                pIBd=__expf(cdt[13]), pIId=__expf(cdt[14]);
    const float dBB=pBBs-pBBd, dIB=pIBs-pIBd, dBI=pBIs-pBId, dII=pIIs-pIId;

    // consumer state
    float xB=0.f, xI=0.f, xO=1.f;          // lane / uniform partition (scaled)
    float XBp=0.f, XIp=0.f;                // X(t-1)
    float phBp=0.f, phIp=0.f;              // phi(t-1)
    float pOOx=pOO;                        // pOO*xO(t-1)
    float rr=1.f; int keC=0;               // r(t) and its exponent
    float zB=0.f, zI=0.f;                  // z(t) (pre-reduction lane values)
    float gBc=0.f, gIc=0.f;                // g(t)
    float raB=0.f, raI=0.f;                // in-flight DPP results for S(t)
    float fOc=0.f;                         // fO(t)
    float accF=0.f; int accE=0;
    float f0B=0,f0I=0,f0O=0, f1B=0,f1I=0,f1O=0, f2B=0,f2I=0,f2O=0, f3B=0,f3I=0,f3O=0;
    int w3 = 0;
    float gs = 0.f;                        // gold partial (wave 2)

    // gold-wave helper: compute G pairs for one chunk (8-way zipped reductions)
    auto do_G = [&](int chunkIdx) {
        const int par = chunkIdx & 1;
        const int tbase = 1 + chunkIdx * CHUNK;
        #pragma unroll
        for (int kk = 0; kk < CHUNK; kk += 4) {
            const float* r0 = &S[(size_t)((tbase + kk + 0 - 1) & 63) << 7];
            const float* r1 = &S[(size_t)((tbase + kk + 1 - 1) & 63) << 7];
            const float* r2 = &S[(size_t)((tbase + kk + 2 - 1) & 63) << 7];
            const float* r3 = &S[(size_t)((tbase + kk + 3 - 1) & 63) << 7];
            float o0 = r0[50], o1 = r1[50], o2 = r2[50], o3 = r3[50];
            float g0 = actm*__expf(r0[l]-o0), h0 = actm*__expf(r0[64+l]-o0);
            float g1 = actm*__expf(r1[l]-o1), h1 = actm*__expf(r1[64+l]-o1);
            float g2 = actm*__expf(r2[l]-o2), h2 = actm*__expf(r2[64+l]-o2);
            float g3 = actm*__expf(r3[l]-o3), h3 = actm*__expf(r3[64+l]-o3);
#define GSTAGE(C) g0=dpp_xadd<C>(g0); h0=dpp_xadd<C>(h0); g1=dpp_xadd<C>(g1); h1=dpp_xadd<C>(h1); \
                  g2=dpp_xadd<C>(g2); h2=dpp_xadd<C>(h2); g3=dpp_xadd<C>(g3); h3=dpp_xadd<C>(h3);
            GSTAGE(0xB1) GSTAGE(0x4E) GSTAGE(0x141) GSTAGE(0x140) GSTAGE(0x142) GSTAGE(0x143)
#undef GSTAGE
            float G0=rdl63(g0), H0=rdl63(h0), G1=rdl63(g1), H1=rdl63(h1);
            float G2=rdl63(g2), H2=rdl63(h2), G3=rdl63(g3), H3=rdl63(h3);
            if (l == 0) {
                Gbuf[par][kk+0] = make_float2(G0,H0);
                Gbuf[par][kk+1] = make_float2(G1,H1);
                Gbuf[par][kk+2] = make_float2(G2,H2);
                Gbuf[par][kk+3] = make_float2(G3,H3);
            }
        }
    };

    if (wave == 1) {
        #pragma unroll
        for (int k = 0; k < 2*CHUNK; ++k) {   // stage chunks 0,1 (steps 1..32)
            const float* row = fb + (size_t)(1 + k) * T;
            float* dst = &S[(size_t)k * 128];
            gl_lds(row + s1, dst);
            gl_lds(row + s2, dst + 64);
        }
    } else if (wave == 0) {
        float pO0 = fb[0] + start_t[0];
        xB = actm * __expf(fb[aB] + start_t[aB] - pO0);
        xI = actm * __expf(fb[aI] + start_t[aI] - pO0);
        accF = pO0;
    } else {
        if (l == 0) { int tg0 = tb[0]; gs = fb[tg0] + start_t[tg0]; }
    }
    __syncthreads();   // #1: chunks 0,1 staged

    if (wave == 0) {
        // ---- prologue: X(0), phi(0), rows 1..3, g(1), z(1), launch S(1) ----
        XBp = wsum64(xB); XIp = wsum64(xI);
        phBp = __builtin_fmaf(pIBd, XIp, __builtin_fmaf(pBBd, XBp, pOB));  // xO(0)=1
        phIp = __builtin_fmaf(pIId, XIp, __builtin_fmaf(pBId, XBp, pOI));
        pOOx = pOO; xO = 1.f;
        float r1B=S[l], r1I=S[64+l], r1O=S[50];              // row 1
        f3B=S[128+l]; f3I=S[128+64+l]; f3O=S[128+50];        // row 2
        f0B=S[256+l]; f0I=S[256+64+l]; f0O=S[256+50];        // row 3
        gBc = actm * __expf(r1B - r1O);
        gIc = actm * __expf(r1I - r1O);
        fOc = r1O;
        float tB0 = __builtin_fmaf(dIB, xI, dBB * xB);
        float tI0 = __builtin_fmaf(dII, xI, dBI * xB);
        zB = gBc * tB0; zI = gIc * tI0;
        raB = dpp_xadd<0xB1>(zB);  raI = dpp_xadd<0xB1>(zI);
        raB = dpp_xadd<0x4E>(raB); raI = dpp_xadd<0x4E>(raI);
        raB = dpp_xadd<0x141>(raB);raI = dpp_xadd<0x141>(raI);
        raB = dpp_xadd<0x140>(raB);raI = dpp_xadd<0x140>(raI);
        raB = dpp_xadd<0x142>(raB);raI = dpp_xadd<0x142>(raI);
        raB = dpp_xadd<0x143>(raB);raI = dpp_xadd<0x143>(raI);
        rr = 1.f; keC = 0; w3 = 256;
    } else if (wave == 2) {
        do_G(0);    // G for chunk 0
    }
    __syncthreads();   // #2: Gbuf chunk 0 ready

// One pipelined step (lag-1). BLOCK A: finish x(t), compute z(t+1), launch
// S(t+1), LDS reads (fillers between DPP stages). BLOCK B: consume S(t),
// finish X(t), xO(t), phi(t), next rescale.
#define PHASE(K, cB_,cI_,cO_, nB_,nI_,nO_, Gu_,Gv_)                            \
    {                                                                          \
        float xBn = __builtin_fmaf(gBc, phBp, zB) * rr;                        \
        float xIn = __builtin_fmaf(gIc, phIp, zI) * rr;                        \
        float eBt = __expf(cB_ - cO_);                                         \
        float eIt = __expf(cI_ - cO_);                                         \
        float tBv = __builtin_fmaf(dIB, xIn, dBB * xBn);                       \
        float tIv = __builtin_fmaf(dII, xIn, dBI * xBn);                       \
        float gBn = actm * eBt;                                                \
        float gIn = actm * eIt;                                                \
        float zBn = gBn * tBv;                                                 \
        float zIn = gIn * tIv;                                                 \
        float qB = dpp_xadd<0xB1>(zBn);                                        \
        float qI = dpp_xadd<0xB1>(zIn);                                        \
        w3 = (w3 + 128) & 8191;                                                \
        nB_ = S[w3 + l];                                                       \
        qB = dpp_xadd<0x4E>(qB);                                               \
        qI = dpp_xadd<0x4E>(qI);                                               \
        nI_ = S[w3 + 64 + l];                                                  \
        qB = dpp_xadd<0x141>(qB);                                              \
        qI = dpp_xadd<0x141>(qI);                                              \
        nO_ = S[w3 + 50];                                                      \
        qB = dpp_xadd<0x140>(qB);                                              \
        qI = dpp_xadd<0x140>(qI);                                              \
        Gv_ = Gr[(K) + 1];                                                     \
        qB = dpp_xadd<0x142>(qB);                                              \
        qI = dpp_xadd<0x142>(qI);                                              \
        accF += fOc;                                                           \
        accE += keC;                                                           \
        qB = dpp_xadd<0x143>(qB);                                              \
        qI = dpp_xadd<0x143>(qI);                                              \
        __builtin_amdgcn_sched_barrier(0);                                     \
        float SBr = rdl63(raB);                                                \
        float SIr = rdl63(raI);                                                \
        float XBn = __builtin_fmaf(Gu_.x, phBp, SBr) * rr;                     \
        float XIn = __builtin_fmaf(Gu_.y, phIp, SIr) * rr;                     \
        float xOn = rr * __builtin_fmaf(pIO, XIp, __builtin_fmaf(pBO, XBp, pOOx)); \
        float pOBx = pOB * xOn;                                                \
        float pOIx = pOI * xOn;                                                \
        pOOx = pOO * xOn;                                                      \
        float phBn = __builtin_fmaf(pIBd, XIn, __builtin_fmaf(pBBd, XBn, pOBx)); \
        float phIn = __builtin_fmaf(pIId, XIn, __builtin_fmaf(pBId, XBn, pOIx)); \
        int ike = ((__float_as_int(xOn) >> 23) & 0xFF) - 127;                  \
        rr = __int_as_float((127 - ike) << 23);                                \
        keC = ike;                                                             \
        xB = xBn; xI = xIn; zB = zBn; zI = zIn;                                \
        gBc = gBn; gIc = gIn; raB = qB; raI = qI;                              \
        XBp = XBn; XIp = XIn; xO = xOn;                                        \
        phBp = phBn; phIp = phIn; fOc = cO_;                                   \
    }

    for (int p = 0; p < nper; ++p) {
        if (wave == 0) {
            if (p < nfull) {
                const float2* Gr = &Gbuf[p & 1][0];
                float2 rGa = Gr[0];
                float2 rGb = rGa;
                PHASE(0,  f3B,f3I,f3O, f1B,f1I,f1O, rGa, rGb)
                PHASE(1,  f0B,f0I,f0O, f2B,f2I,f2O, rGb, rGa)
                PHASE(2,  f1B,f1I,f1O, f3B,f3I,f3O, rGa, rGb)
                PHASE(3,  f2B,f2I,f2O, f0B,f0I,f0O, rGb, rGa)
                PHASE(4,  f3B,f3I,f3O, f1B,f1I,f1O, rGa, rGb)
                PHASE(5,  f0B,f0I,f0O, f2B,f2I,f2O, rGb, rGa)
                PHASE(6,  f1B,f1I,f1O, f3B,f3I,f3O, rGa, rGb)
                PHASE(7,  f2B,f2I,f2O, f0B,f0I,f0O, rGb, rGa)
                PHASE(8,  f3B,f3I,f3O, f1B,f1I,f1O, rGa, rGb)
                PHASE(9,  f0B,f0I,f0O, f2B,f2I,f2O, rGb, rGa)
                PHASE(10, f1B,f1I,f1O, f3B,f3I,f3O, rGa, rGb)
                PHASE(11, f2B,f2I,f2O, f0B,f0I,f0O, rGb, rGa)
                PHASE(12, f3B,f3I,f3O, f1B,f1I,f1O, rGa, rGb)
                PHASE(13, f0B,f0I,f0O, f2B,f2I,f2O, rGb, rGa)
                PHASE(14, f1B,f1I,f1O, f3B,f3I,f3O, rGa, rGb)
                PHASE(15, f2B,f2I,f2O, f0B,f0I,f0O, rGb, rGa)
            } else {
                // tail: plain lag-0 body (r14-verbatim); pending rr/keC unused,
                // tail recomputes its own rescale from xO (accE consistent).
                for (int k = 0; k < CHUNK; ++k) {
                    int t = 1 + p * CHUNK + k;
                    if (t <= nsteps) {
                        const float* row = &S[(size_t)(((t - 1) & 63)) << 7];
                        float fBv = row[l], fIv = row[64 + l], fOv = row[50];
                        float gB = actm * __expf(fBv - fOv);
                        float gI = actm * __expf(fIv - fOv);
                        float pOBx = pOB * xO, pOIx = pOI * xO, pOOx2 = pOO * xO;
                        float uB = __builtin_fmaf(xB, dBB, __builtin_fmaf(xI, dIB, pOBx));
                        float uI = __builtin_fmaf(xB, dBI, __builtin_fmaf(xI, dII, pOIx));
                        int   ke  = ((__float_as_int(xO) >> 23) & 0xFF) - 127;
                        float rsc = __int_as_float((127 - ke) << 23);
                        accE += ke; accF += fOv;
                        float XBt = wsum64(xB);
                        float XIt = wsum64(xI);
                        float NO = __builtin_fmaf(XIt, pIO, __builtin_fmaf(XBt, pBO, pOOx2));
                        float NB = gB * __builtin_fmaf(XIt, pIBd, __builtin_fmaf(XBt, pBBd, uB));
                        float NI = gI * __builtin_fmaf(XIt, pIId, __builtin_fmaf(XBt, pBId, uI));
                        xB = NB * rsc; xI = NI * rsc; xO = NO * rsc;
                    }
                }
            }
        } else if (wave == 1) {
            const int ci = p + 2;                  // stage chunk p+2
            #pragma unroll
            for (int k = 0; k < CHUNK; ++k) {
                int t = 1 + ci * CHUNK + k;
                t = (t < SEQ) ? t : (SEQ - 1);     // clamp; rows beyond len unused
                const float* row = fb + (size_t)t * T;
                float* dst = &S[(size_t)((ci * CHUNK + k) & 63) * 128];
                gl_lds(row + s1, dst);
                gl_lds(row + s2, dst + 64);
            }
        } else {
            do_G(p + 1);                           // G for chunk p+1 (next period's)
            // gold-score: chunk p-1 (rows live until period p+1)
            if (p >= 1 && l < CHUNK) {
                int t = 1 + (p - 1) * CHUNK + l;
                if (t <= nsteps) {
                    int tg = tb[t], tp = tb[t - 1];
                    int c1 = (tp == 0) ? 0 : ((tp & 1) ? 1 : 2);
                    int c2 = (tg == 0) ? 0 : ((tg & 1) ? 1 : 2);
                    int si = (tp - 1) >> 1, sj = (tg - 1) >> 1;
                    int t1 = (tp != 0 && si != sj) ? ((c2 == 0) ? 0 : c2 + 2) : c2;
                    gs += cdt[c1 * 5 + t1];
                    int idx = (tg == 0) ? 50 : ((tg & 1) ? ((tg - 1) >> 1) : (64 + ((tg - 2) >> 1)));
                    gs += S[(((t - 1) & 63) << 7) + idx];
                }
            }
        }
        __syncthreads();
    }
#undef PHASE

    if (wave == 0) {
        // forward = accF + ln2*accE + ln( sum_j x_j * exp(stop_j) )
        float W = actm * (xB * __expf(stop_t[aB]) + xI * __expf(stop_t[aI]));
        float tot = wsum64(W) + xO * __expf(stop_t[0]);
        float fwd = accF + 0.69314718055994530942f * (float)accE + __logf(tot);
        if (l == 0) res[0] = fwd;
    } else if (wave == 2) {
        // final chunk (nper-1): its rows are still intact after the loop
        if (l < CHUNK) {
            int t = 1 + (nper - 1) * CHUNK + l;
            if (t >= 1 && t <= nsteps) {
                int tg = tb[t], tp = tb[t - 1];
                int c1 = (tp == 0) ? 0 : ((tp & 1) ? 1 : 2);
                int c2 = (tg == 0) ? 0 : ((tg & 1) ? 1 : 2);
                int si = (tp - 1) >> 1, sj = (tg - 1) >> 1;
                int t1 = (tp != 0 && si != sj) ? ((c2 == 0) ? 0 : c2 + 2) : c2;
                gs += cdt[c1 * 5 + t1];
                int idx = (tg == 0) ? 50 : ((tg & 1) ? ((tg - 1) >> 1) : (64 + ((tg - 2) >> 1)));
                gs += S[(((t - 1) & 63) << 7) + idx];
            }
        }
        float gold = wsum64(gs);
        if (l == 0) res[1] = gold + stop_t[tb[len - 1]];
    }
    __syncthreads();
    if (tid == 0) out[b] = res[0] - res[1];
}

extern "C" void kernel_launch(void* const* d_in, const int* in_sizes, int n_in,
                              void* d_out, int out_size, void* d_ws, size_t ws_size,
                              hipStream_t stream) {
    const float* feats   = (const float*)d_in[0];
    const float* cdt     = (const float*)d_in[1];
    const float* start_t = (const float*)d_in[2];
    const float* stop_t  = (const float*)d_in[3];
    const int*   mask    = (const int*)d_in[4];
    const int*   tags    = (const int*)d_in[5];
    float* out = (float*)d_out;

    crf_nll_kernel<<<256, 192, 0, stream>>>(feats, cdt, start_t, stop_t, mask, tags, out);
}

// Round 17
// 223.251 us; speedup vs baseline: 1.2283x; 1.2283x over previous
//
#include <hip/hip_runtime.h>
#include <math.h>

#define NSLOTS 50
#define T 101
#define SEQ 2048
#define CHUNK 16

// v + dpp_permuted(v), pure VALU
template<int CTRL>
__device__ __forceinline__ float dpp_xadd(float v) {
    int x = __builtin_amdgcn_update_dpp(0, __float_as_int(v), CTRL, 0xF, 0xF, true);
    return v + __int_as_float(x);
}

// Full 64-lane sum -> wave-uniform scalar (validated r8-r14, absmax 0.0)
__device__ __forceinline__ float wsum64(float v) {
    v = dpp_xadd<0xB1>(v);    // xor 1
    v = dpp_xadd<0x4E>(v);    // xor 2
    v = dpp_xadd<0x141>(v);   // xor 4 (row_half_mirror)
    v = dpp_xadd<0x140>(v);   // xor 8 (row_mirror)
    v = dpp_xadd<0x142>(v);   // row_bcast15
    v = dpp_xadd<0x143>(v);   // row_bcast31
    int s = __builtin_amdgcn_readlane(__float_as_int(v), 63);
    return __int_as_float(s);
}

__device__ __forceinline__ void gl_lds(const float* g, float* lds) {
#if __has_builtin(__builtin_amdgcn_global_load_lds)
    __builtin_amdgcn_global_load_lds((const __attribute__((address_space(1))) void*)g,
        (__attribute__((address_space(3))) void*)lds, 4, 0, 0);
#else
    lds[threadIdx.x & 63] = *g;
#endif
}

__global__ __launch_bounds__(192, 1) void crf_nll_kernel(
    const float* __restrict__ feats,      // [B,S,T]
    const float* __restrict__ cdt,        // [3,5] log-probs
    const float* __restrict__ start_t,    // [T]
    const float* __restrict__ stop_t,     // [T]
    const int*   __restrict__ mask,       // [B,S]
    const int*   __restrict__ tags,       // [B,S]
    float*       __restrict__ out)        // [B]
{
    const int b = blockIdx.x, tid = threadIdx.x;
    const int wave = tid >> 6, l = tid & 63;
    const float* fb = feats + (size_t)b * SEQ * T;
    const int*   mb = mask + (size_t)b * SEQ;
    const int*   tb = tags + (size_t)b * SEQ;

    __shared__ float S[64 * 128];   // ring: step t -> slot (t-1)&63
    __shared__ float res[2];

    // ---- length (all waves; mask is a prefix of ones) ----
    float mc = 0.f;
    for (int t = l; t < SEQ; t += 64) mc += (float)mb[t];
    const int len    = (int)(wsum64(mc) + 0.5f);
    const int nsteps = len - 1;
    const int nper   = (nsteps + CHUNK - 1) / CHUNK;
    const int nfull  = nsteps / CHUNK;

    const float actm = (l < NSLOTS) ? 1.f : 0.f;
    const int aB = (2*l+1 <= 100) ? 2*l+1 : 100;
    const int aI = (2*l+2 <= 100) ? 2*l+2 : 100;
    const int s1 = (2*l+1 <= 100) ? 2*l+1 : 0;
    const int s2 = (2*l+2 <= 100) ? 2*l+2 : 0;

    const float pOO=__expf(cdt[0]),  pOB=__expf(cdt[1]),  pOI=__expf(cdt[2]);
    const float pBO=__expf(cdt[5]),  pBBs=__expf(cdt[6]), pBIs=__expf(cdt[7]),
                pBBd=__expf(cdt[8]), pBId=__expf(cdt[9]);
    const float pIO=__expf(cdt[10]), pIBs=__expf(cdt[11]), pIIs=__expf(cdt[12]),
                pIBd=__expf(cdt[13]), pIId=__expf(cdt[14]);
    const float dBB=pBBs-pBBd, dIB=pIBs-pIBd, dBI=pBIs-pBId, dII=pIIs-pIId;

    // consumer state (r9-verbatim semantics)
    float xB=0.f, xI=0.f, xO=1.f, accF=0.f, uB=0.f, uI=0.f, pOOxO=pOO;
    int accE = 0;
    float f0B=0,f0I=0,f0O=0, f1B=0,f1I=0,f1O=0, f2B=0,f2I=0,f2O=0;
    float gs = 0.f;   // gold partial (wave 2)

    if (wave == 1) {
        // stage chunks 0,1 (rows for steps t=1..32)
        #pragma unroll
        for (int k = 0; k < 2*CHUNK; ++k) {
            const float* row = fb + (size_t)(1 + k) * T;
            float* dst = &S[(size_t)k * 128];
            gl_lds(row + s1, dst);
            gl_lds(row + s2, dst + 64);
        }
    } else if (wave == 0) {
        float pO0 = fb[0] + start_t[0];
        xB = actm * __expf(fb[aB] + start_t[aB] - pO0);
        xI = actm * __expf(fb[aI] + start_t[aI] - pO0);
        accF = pO0;
        uB = __builtin_fmaf(xB, dBB, __builtin_fmaf(xI, dIB, pOB));
        uI = __builtin_fmaf(xB, dBI, __builtin_fmaf(xI, dII, pOI));
    } else {
        if (l == 0) { int tg0 = tb[0]; gs = fb[tg0] + start_t[tg0]; }
    }
    __syncthreads();   // chunks 0,1 staged

    if (wave == 0) {   // pipeline fill: steps 1,2,3 (3-deep LDS->reg pipeline)
        f0B = S[l];         f0I = S[64 + l];         f0O = S[50];
        f1B = S[128 + l];   f1I = S[128 + 64 + l];   f1O = S[128 + 50];
        f2B = S[256 + l];   f2I = S[256 + 64 + l];   f2O = S[256 + 50];
    }

// r9 algebra, re-ordered: the two 6-stage DPP reductions are hand-zipped
// (xB/xI alternating) with all independent per-step work (LDS reads for
// step t+3, the two g-exps, rescale int ops) placed BETWEEN the dependent
// DPP stages in program order -- covers in-order-issue stalls.
#define STEP_BODY(GUARDED)                                                     \
    {                                                                          \
        const int t  = 1 + p * CHUNK + k;                                      \
        const int w3 = ((t + 2) & 63) << 7;   /* slot of step t+3 */           \
        float ra_ = xB, rc_ = xI;                                              \
        ra_ = dpp_xadd<0xB1>(ra_);   rc_ = dpp_xadd<0xB1>(rc_);                \
        float nB_ = S[w3 + l];                                                 \
        ra_ = dpp_xadd<0x4E>(ra_);   rc_ = dpp_xadd<0x4E>(rc_);                \
        float nI_ = S[w3 + 64 + l];                                            \
        ra_ = dpp_xadd<0x141>(ra_);  rc_ = dpp_xadd<0x141>(rc_);               \
        float nO_ = S[w3 + 50];                                                \
        ra_ = dpp_xadd<0x140>(ra_);  rc_ = dpp_xadd<0x140>(rc_);               \
        float gB = actm * __expf(f0B - f0O);                                   \
        ra_ = dpp_xadd<0x142>(ra_);  rc_ = dpp_xadd<0x142>(rc_);               \
        float gI = actm * __expf(f0I - f0O);                                   \
        ra_ = dpp_xadd<0x143>(ra_);  rc_ = dpp_xadd<0x143>(rc_);               \
        int   ke  = ((__float_as_int(xO) >> 23) & 0xFF) - 127;                 \
        float rsc = __int_as_float((127 - ke) << 23);   /* 2^-ke, exact */     \
        float XB = __int_as_float(__builtin_amdgcn_readlane(__float_as_int(ra_), 63)); \
        float XI = __int_as_float(__builtin_amdgcn_readlane(__float_as_int(rc_), 63)); \
        if (!(GUARDED) || t <= nsteps) {                                       \
            float NO = __builtin_fmaf(XI,pIO, __builtin_fmaf(XB,pBO, pOOxO));  \
            float NB = gB * __builtin_fmaf(XI,pIBd, __builtin_fmaf(XB,pBBd, uB)); \
            float NI = gI * __builtin_fmaf(XI,pIId, __builtin_fmaf(XB,pBId, uI)); \
            xB = NB * rsc; xI = NI * rsc; xO = NO * rsc;                       \
            accE += ke;                                                        \
            pOOxO = pOO * xO;                                                  \
            uB = __builtin_fmaf(xB, dBB, __builtin_fmaf(xI, dIB, pOB * xO));   \
            uI = __builtin_fmaf(xB, dBI, __builtin_fmaf(xI, dII, pOI * xO));   \
            accF += f0O;                                                       \
        }                                                                      \
        f0B=f1B; f0I=f1I; f0O=f1O; f1B=f2B; f1I=f2I; f1O=f2O;                  \
        f2B=nB_; f2I=nI_; f2O=nO_;                                             \
    }

    for (int p = 0; p < nper; ++p) {
        if (wave == 0) {
            if (p < nfull) {
                #pragma unroll
                for (int k = 0; k < CHUNK; ++k) STEP_BODY(false)
            } else {
                #pragma unroll
                for (int k = 0; k < CHUNK; ++k) STEP_BODY(true)
            }
        } else if (wave == 1) {
            const int ci = p + 2;                  // stage chunk p+2
            #pragma unroll
            for (int k = 0; k < CHUNK; ++k) {
                int t = 1 + ci * CHUNK + k;
                t = (t < SEQ) ? t : (SEQ - 1);     // clamp; rows beyond len unused
                const float* row = fb + (size_t)t * T;
                float* dst = &S[(size_t)((ci * CHUNK + k) & 63) * 128];
                gl_lds(row + s1, dst);
                gl_lds(row + s2, dst + 64);
            }
        } else {
            // gold wave: chunk p-1 (rows live until period p+1)
            if (p >= 1 && l < CHUNK) {
                int t = 1 + (p - 1) * CHUNK + l;
                if (t <= nsteps) {
                    int tg = tb[t], tp = tb[t - 1];
                    int c1 = (tp == 0) ? 0 : ((tp & 1) ? 1 : 2);
                    int c2 = (tg == 0) ? 0 : ((tg & 1) ? 1 : 2);
                    int si = (tp - 1) >> 1, sj = (tg - 1) >> 1;
                    int t1 = (tp != 0 && si != sj) ? ((c2 == 0) ? 0 : c2 + 2) : c2;
                    gs += cdt[c1 * 5 + t1];
                    int idx = (tg == 0) ? 50 : ((tg & 1) ? ((tg - 1) >> 1) : (64 + ((tg - 2) >> 1)));
                    gs += S[(((t - 1) & 63) << 7) + idx];
                }
            }
        }
        __syncthreads();
    }
#undef STEP_BODY

    if (wave == 0) {
        // forward = accF + ln2*accE + ln( sum_j x_j * exp(stop_j) )
        float W = actm * (xB * __expf(stop_t[aB]) + xI * __expf(stop_t[aI]));
        float tot = wsum64(W) + xO * __expf(stop_t[0]);
        float fwd = accF + 0.69314718055994530942f * (float)accE + __logf(tot);
        if (l == 0) res[0] = fwd;
    } else if (wave == 2) {
        // final chunk (nper-1): its rows are still intact after the loop
        if (l < CHUNK) {
            int t = 1 + (nper - 1) * CHUNK + l;
            if (t >= 1 && t <= nsteps) {
                int tg = tb[t], tp = tb[t - 1];
                int c1 = (tp == 0) ? 0 : ((tp & 1) ? 1 : 2);
                int c2 = (tg == 0) ? 0 : ((tg & 1) ? 1 : 2);
                int si = (tp - 1) >> 1, sj = (tg - 1) >> 1;
                int t1 = (tp != 0 && si != sj) ? ((c2 == 0) ? 0 : c2 + 2) : c2;
                gs += cdt[c1 * 5 + t1];
                int idx = (tg == 0) ? 50 : ((tg & 1) ? ((tg - 1) >> 1) : (64 + ((tg - 2) >> 1)));
                gs += S[(((t - 1) & 63) << 7) + idx];
            }
        }
        float gold = wsum64(gs);
        if (l == 0) res[1] = gold + stop_t[tb[len - 1]];
    }
    __syncthreads();
    if (tid == 0) out[b] = res[0] - res[1];
}

extern "C" void kernel_launch(void* const* d_in, const int* in_sizes, int n_in,
                              void* d_out, int out_size, void* d_ws, size_t ws_size,
                              hipStream_t stream) {
    const float* feats   = (const float*)d_in[0];
    const float* cdt     = (const float*)d_in[1];
    const float* start_t = (const float*)d_in[2];
    const float* stop_t  = (const float*)d_in[3];
    const int*   mask    = (const int*)d_in[4];
    const int*   tags    = (const int*)d_in[5];
    float* out = (float*)d_out;

    crf_nll_kernel<<<256, 192, 0, stream>>>(feats, cdt, start_t, stop_t, mask, tags, out);
}